// Round 6
// baseline (240.675 us; speedup 1.0000x reference)
//
#include <hip/hip_runtime.h>
#include <hip/hip_bf16.h>
#include <cstdint>
#include <cstddef>

// Problem constants
#define BB 2
#define SS 2048
#define DD 1024
#define HH 16
#define HD 64

typedef __attribute__((ext_vector_type(8))) short bf16x8;
typedef __attribute__((ext_vector_type(4))) short bf16x4;
typedef __attribute__((ext_vector_type(4))) float f32x4;

// 16x16x16 bf16 MFMA: canonical ROCm spelling (gfx90a..gfx950), 4 bf16/operand.
// NOTE: __has_builtin is unreliable for target builtins on the host pass — use
// the name unconditionally (builtins are declared on both passes).
#define MFMA16(va, vb, c) __builtin_amdgcn_mfma_f32_16x16x16bf16_1k(va, vb, c, 0, 0, 0)

// async global->LDS, 16B per lane, dest = wave-uniform base + lane*16
#define GLL(g, l) __builtin_amdgcn_global_load_lds( \
    (const __attribute__((address_space(1))) void*)(g), \
    (__attribute__((address_space(3))) void*)(l), 16, 0, 0)

// fast RTNE f32->bf16 (inputs guaranteed non-NaN in this problem)
__device__ __forceinline__ short f2bf_fast(float f) {
    uint32_t u = __float_as_uint(f);
    u += 0x7FFF + ((u >> 16) & 1);
    return (short)(u >> 16);
}
__device__ __forceinline__ uint32_t pack_bf2(float a, float b) {
    uint32_t ua = __float_as_uint(a), ub = __float_as_uint(b);
    ua += 0x7FFF + ((ua >> 16) & 1);
    ub += 0x7FFF + ((ub >> 16) & 1);
    return (ua >> 16) | (ub & 0xFFFF0000u);
}
// 8 fp32 -> 8 bf16 via two float4 loads, packed
__device__ __forceinline__ bf16x8 cvt8(const float* __restrict__ p) {
    float4 a = *(const float4*)p;
    float4 b = *(const float4*)(p + 4);
    union { uint32_t d[4]; bf16x8 v; } r;
    r.d[0] = pack_bf2(a.x, a.y);
    r.d[1] = pack_bf2(a.z, a.w);
    r.d[2] = pack_bf2(b.x, b.y);
    r.d[3] = pack_bf2(b.z, b.w);
    return r.v;
}

// ---------------- fp32 -> bf16 pre-convert (6 tensors, one dispatch) --------
__global__ __launch_bounds__(256) void cvt6_kernel(
    const float* __restrict__ s0, const float* __restrict__ s1,
    const float* __restrict__ s2, const float* __restrict__ s3,
    const float* __restrict__ s4, const float* __restrict__ s5,
    short* __restrict__ d0, short* __restrict__ d1, short* __restrict__ d2,
    short* __restrict__ d3, short* __restrict__ d4, short* __restrict__ d5)
{
    const int z = blockIdx.z;
    const float* s = (z == 0) ? s0 : (z == 1) ? s1 : (z == 2) ? s2
                   : (z == 3) ? s3 : (z == 4) ? s4 : s5;
    short* d = (z == 0) ? d0 : (z == 1) ? d1 : (z == 2) ? d2
             : (z == 3) ? d3 : (z == 4) ? d4 : d5;
    const int n8 = (z < 2) ? (BB * SS * DD / 8) : (DD * DD / 8);
    const int id = blockIdx.x * 256 + threadIdx.x;
    if (id >= n8) return;
    bf16x8 r = cvt8(s + (size_t)id * 8);
    *(uint4*)(d + (size_t)id * 8) = *(uint4*)&r;
}

// ---------------- fused QKV GEMM: 128x128 tile, z selects Q/K/V -------------
// z=0: Q -> [B,H,S,HD]; z=1: K -> [B,H,S,HD]; z=2: V -> [B,H,HD,S] (transposed)
template<int BF>
__global__ __launch_bounds__(256, 3) void qkv_gemm_kernel(
    const void* __restrict__ dec, const void* __restrict__ enc,
    const void* __restrict__ Wq, const void* __restrict__ Wk,
    const void* __restrict__ Wv,
    const float* __restrict__ bq, const float* __restrict__ bk,
    const float* __restrict__ bv,
    short* __restrict__ Qo, short* __restrict__ Ko, short* __restrict__ Vo)
{
    __shared__ short As[128 * 32];   // unpadded: required by global_load_lds
    __shared__ short Bs[128 * 32];

    const int z = blockIdx.z;
    const void* Xv = (z == 0) ? dec : enc;
    const void* Wp_ = (z == 0) ? Wq : (z == 1) ? Wk : Wv;
    const float* bias = (z == 0) ? bq : (z == 1) ? bk : bv;
    short* Yo = (z == 0) ? Qo : (z == 1) ? Ko : Vo;

    const int t = threadIdx.x;
    const int lane = t & 63, wv = t >> 6;
    const int lr = lane & 15, quad = lane >> 4;
    const int wm = wv >> 1, wn = wv & 1;
    const int m0 = blockIdx.y * 128;
    const int n0 = blockIdx.x * 128;
    const int K = DD;

    f32x4 acc[4][4];
    #pragma unroll
    for (int i = 0; i < 4; i++)
        #pragma unroll
        for (int j = 0; j < 4; j++) acc[i][j] = (f32x4){0.f, 0.f, 0.f, 0.f};

    for (int kb = 0; kb < K; kb += 32) {
        __syncthreads();
        if (BF) {
            const short* Xb = (const short*)Xv;
            const short* Wb = (const short*)Wp_;
            #pragma unroll
            for (int c = 0; c < 2; c++) {
                int r0 = wv * 32 + c * 16;              // 16 rows x 64B = 1KB/call
                int r = r0 + (lane >> 2), ch = (lane & 3) * 8;
                GLL(Xb + (size_t)(m0 + r) * K + kb + ch, &As[r0 * 32]);
                GLL(Wb + (size_t)(n0 + r) * K + kb + ch, &Bs[r0 * 32]);
            }
        } else {
            const float* Xf = (const float*)Xv;
            const float* Wf = (const float*)Wp_;
            #pragma unroll
            for (int c = 0; c < 2; c++) {
                int id = t + c * 256;
                int r = id >> 2, c8 = (id & 3) * 8;
                *(bf16x8*)&As[r * 32 + c8] = cvt8(Xf + (size_t)(m0 + r) * K + kb + c8);
                *(bf16x8*)&Bs[r * 32 + c8] = cvt8(Wf + (size_t)(n0 + r) * K + kb + c8);
            }
        }
        __syncthreads();

        bf16x8 af[4], bfr[4];
        #pragma unroll
        for (int mi = 0; mi < 4; mi++)
            af[mi] = *(const bf16x8*)&As[(wm * 64 + mi * 16 + lr) * 32 + quad * 8];
        #pragma unroll
        for (int ni = 0; ni < 4; ni++)
            bfr[ni] = *(const bf16x8*)&Bs[(wn * 64 + ni * 16 + lr) * 32 + quad * 8];
        #pragma unroll
        for (int mi = 0; mi < 4; mi++)
            #pragma unroll
            for (int ni = 0; ni < 4; ni++)
                acc[mi][ni] = __builtin_amdgcn_mfma_f32_16x16x32_bf16(
                    af[mi], bfr[ni], acc[mi][ni], 0, 0, 0);
    }

    #pragma unroll
    for (int ni = 0; ni < 4; ni++) {
        int col = n0 + wn * 64 + ni * 16 + lr;
        int h = col >> 6, hd = col & 63;
        float bvv = bias[col];
        #pragma unroll
        for (int mi = 0; mi < 4; mi++) {
            #pragma unroll
            for (int r2 = 0; r2 < 4; r2++) {
                int row = m0 + wm * 64 + mi * 16 + quad * 4 + r2;
                int b = row >> 11, s = row & 2047;
                float v = acc[mi][ni][r2] + bvv;
                size_t off;
                if (z < 2)
                    off = ((size_t)(b * HH + h) * SS + s) * HD + hd;
                else
                    off = ((size_t)(b * HH + h) * HD + hd) * SS + s;
                Yo[off] = f2bf_fast(v);
            }
        }
    }
}

// ---------------- output projection: 64x128 tile (512 blocks = 2/CU) -------
template<int WBF>
__global__ __launch_bounds__(256, 2) void proj_gemm_kernel(
    const short* __restrict__ X,
    const void* __restrict__ W, const float* __restrict__ bias,
    float* __restrict__ Y)
{
    __shared__ short As[64 * 32];
    __shared__ short Bs[128 * 32];

    const int t = threadIdx.x;
    const int lane = t & 63, wv = t >> 6;
    const int lr = lane & 15, quad = lane >> 4;
    const int wm = wv >> 1, wn = wv & 1;
    const int m0 = blockIdx.y * 64;
    const int n0 = blockIdx.x * 128;
    const int K = DD, N = DD;

    f32x4 acc[2][4];
    #pragma unroll
    for (int i = 0; i < 2; i++)
        #pragma unroll
        for (int j = 0; j < 4; j++) acc[i][j] = (f32x4){0.f, 0.f, 0.f, 0.f};

    for (int kb = 0; kb < K; kb += 32) {
        __syncthreads();
        {   // A: 4KB total, 1 call/wave (16 rows)
            int r0 = wv * 16;
            int r = r0 + (lane >> 2), ch = (lane & 3) * 8;
            GLL(X + (size_t)(m0 + r) * K + kb + ch, &As[r0 * 32]);
        }
        if (WBF) {
            const short* Wb = (const short*)W;
            #pragma unroll
            for (int c = 0; c < 2; c++) {
                int r0 = wv * 32 + c * 16;
                int r = r0 + (lane >> 2), ch = (lane & 3) * 8;
                GLL(Wb + (size_t)(n0 + r) * K + kb + ch, &Bs[r0 * 32]);
            }
        } else {
            const float* Wf = (const float*)W;
            #pragma unroll
            for (int c = 0; c < 2; c++) {
                int id = t + c * 256;
                int r = id >> 2, c8 = (id & 3) * 8;
                *(bf16x8*)&Bs[r * 32 + c8] = cvt8(Wf + (size_t)(n0 + r) * K + kb + c8);
            }
        }
        __syncthreads();

        bf16x8 af[2], bfr[4];
        #pragma unroll
        for (int mi = 0; mi < 2; mi++)
            af[mi] = *(const bf16x8*)&As[(wm * 32 + mi * 16 + lr) * 32 + quad * 8];
        #pragma unroll
        for (int ni = 0; ni < 4; ni++)
            bfr[ni] = *(const bf16x8*)&Bs[(wn * 64 + ni * 16 + lr) * 32 + quad * 8];
        #pragma unroll
        for (int mi = 0; mi < 2; mi++)
            #pragma unroll
            for (int ni = 0; ni < 4; ni++)
                acc[mi][ni] = __builtin_amdgcn_mfma_f32_16x16x32_bf16(
                    af[mi], bfr[ni], acc[mi][ni], 0, 0, 0);
    }

    #pragma unroll
    for (int ni = 0; ni < 4; ni++) {
        int col = n0 + wn * 64 + ni * 16 + lr;
        float bvv = bias[col];
        #pragma unroll
        for (int mi = 0; mi < 2; mi++) {
            #pragma unroll
            for (int r2 = 0; r2 < 4; r2++) {
                int row = m0 + wm * 32 + mi * 16 + quad * 4 + r2;
                Y[(size_t)row * N + col] = acc[mi][ni][r2] + bvv;
            }
        }
    }
}

// ---------------- flash attention, register-resident P ---------------------
// Q,K: [B*H, S, HD] bf16.  Vt_g: [B*H, HD, S] bf16.  Y: [B, S, D] bf16.
// S^T = K·Q^T puts q in lane&15, key in quad*4+reg — exactly the B-operand
// layout of 16x16x16 MFMA. exp2 in regs, pack, PV = V^T·P^T -> O^T. No P LDS.
__global__ __launch_bounds__(256, 4) void attn_kernel(
    const short* __restrict__ Q,
    const short* __restrict__ Kgl,
    const short* __restrict__ Vt_g,
    short* __restrict__ Y)
{
    __shared__ short Ks[128][72];     // [key][hd]
    __shared__ short Vt[64][136];     // [hd][key]; 136 keeps rows 16B-aligned

    const int t = threadIdx.x;
    const int lane = t & 63, w = t >> 6;
    const int lr = lane & 15, quad = lane >> 4;

    const int qt = blockIdx.x & 31;
    const int bh = blockIdx.x >> 5;
    const int b = bh >> 4, h = bh & 15;

    const float C = 0.125f * 1.44269504088896f;  // scale * log2(e)

    // Q as B-operand of S^T: element [k=hd=quad*8+j][n=q=lr] — identical
    // register contents to the old A-operand load.
    const short* Qp = Q + ((size_t)bh * SS + qt * 64 + w * 16 + lr) * HD;
    bf16x8 qf0 = *(const bf16x8*)(Qp + quad * 8);
    bf16x8 qf1 = *(const bf16x8*)(Qp + 32 + quad * 8);

    f32x4 o[4];    // O^T: d = dt*16 + quad*4 + reg, q = lr
    #pragma unroll
    for (int i = 0; i < 4; i++) o[i] = (f32x4){0.f, 0.f, 0.f, 0.f};
    float lsum = 0.f;  // per-lane partial row-sum (keys of this quad)

    const uint4* Kg0 = (const uint4*)(Kgl + (size_t)bh * SS * HD);
    const short* Vg0 = Vt_g + (size_t)bh * HD * SS;

    for (int kt = 0; kt < SS / 128; kt++) {
        __syncthreads();   // prior iter's LDS reads done before overwrite
        const uint4* Kg = Kg0 + (size_t)kt * 128 * 8;
        #pragma unroll
        for (int c = 0; c < 4; c++) {           // K tile: 1024 16B chunks
            int id = t + c * 256;
            int row = id >> 3, h8 = id & 7;
            *(uint4*)&Ks[row][h8 * 8] = Kg[id];
        }
        #pragma unroll
        for (int c = 0; c < 4; c++) {           // V^T tile: 1024 16B chunks
            int id = t + c * 256;
            int hd = id >> 4, s16 = id & 15;
            *(uint4*)&Vt[hd][s16 * 8] =
                *(const uint4*)(Vg0 + (size_t)hd * SS + kt * 128 + s16 * 8);
        }
        __syncthreads();

        // S^T = K @ Q^T over 128 keys (8 key-tiles); A = K-frag, B = Q-frag
        f32x4 sc[8];
        #pragma unroll
        for (int nt = 0; nt < 8; nt++) {
            bf16x8 kf0 = *(const bf16x8*)&Ks[nt * 16 + lr][quad * 8];
            bf16x8 kf1 = *(const bf16x8*)&Ks[nt * 16 + lr][32 + quad * 8];
            sc[nt] = __builtin_amdgcn_mfma_f32_16x16x32_bf16(
                kf0, qf0, (f32x4){0.f, 0.f, 0.f, 0.f}, 0, 0, 0);
            sc[nt] = __builtin_amdgcn_mfma_f32_16x16x32_bf16(kf1, qf1, sc[nt], 0, 0, 0);
        }

        // P^T = exp2(S^T * C) in registers; pack straight into 16x16x16 B-frags
        bf16x4 pb[8];
        #pragma unroll
        for (int nt = 0; nt < 8; nt++) {
            float p0 = __builtin_amdgcn_exp2f(sc[nt][0] * C);
            float p1 = __builtin_amdgcn_exp2f(sc[nt][1] * C);
            float p2 = __builtin_amdgcn_exp2f(sc[nt][2] * C);
            float p3 = __builtin_amdgcn_exp2f(sc[nt][3] * C);
            lsum += (p0 + p1) + (p2 + p3);
            union { uint32_t d[2]; bf16x4 v; } u;
            u.d[0] = pack_bf2(p0, p1);
            u.d[1] = pack_bf2(p2, p3);
            pb[nt] = u.v;
        }

        // O^T += V^T @ P^T  (A = V^T frag [d][key], B = pb)
        #pragma unroll
        for (int dt = 0; dt < 4; dt++) {
            #pragma unroll
            for (int nt = 0; nt < 8; nt++) {
                bf16x4 va = *(const bf16x4*)&Vt[dt * 16 + lr][nt * 16 + quad * 4];
                o[dt] = MFMA16(va, pb[nt], o[dt]);
            }
        }
    }

    // full row-sum: combine the 4 quads holding q=lr
    lsum += __shfl_xor(lsum, 16, 64);
    lsum += __shfl_xor(lsum, 32, 64);
    float inv = 1.0f / lsum;

    // O^T -> Y[b][s=q][h*64+d]; per lane: 4 dt x 4 consecutive d -> 8B stores
    const int srow = qt * 64 + w * 16 + lr;
    short* Yp = Y + ((size_t)b * SS + srow) * DD + h * 64 + quad * 4;
    #pragma unroll
    for (int dt = 0; dt < 4; dt++) {
        union { uint32_t d[2]; } u;
        u.d[0] = pack_bf2(o[dt][0] * inv, o[dt][1] * inv);
        u.d[1] = pack_bf2(o[dt][2] * inv, o[dt][3] * inv);
        *(uint2*)(Yp + dt * 16) = *(uint2*)&u;
    }
}

extern "C" void kernel_launch(void* const* d_in, const int* in_sizes, int n_in,
                              void* d_out, int out_size, void* d_ws, size_t ws_size,
                              hipStream_t stream) {
    const float* dec = (const float*)d_in[0];
    const float* enc = (const float*)d_in[1];
    const float* Wq  = (const float*)d_in[2];
    const float* bq  = (const float*)d_in[3];
    const float* Wk  = (const float*)d_in[4];
    const float* bk  = (const float*)d_in[5];
    const float* Wv  = (const float*)d_in[6];
    const float* bv  = (const float*)d_in[7];
    const float* Wp  = (const float*)d_in[8];
    const float* bp  = (const float*)d_in[9];

    const size_t per = (size_t)BB * HH * SS * HD;  // 4,194,304
    const size_t wsz = (size_t)DD * DD;            // 1,048,576
    short* ws = (short*)d_ws;
    short* Qb  = ws;
    short* Kb  = ws + per;
    short* Vtb = ws + 2 * per;
    short* Yb  = ws + 3 * per;

    dim3 qkv_grid(DD / 128, (BB * SS) / 128, 3);   // 768 blocks = 3/CU exactly
    dim3 proj_grid(DD / 128, (BB * SS) / 64);      // 512 blocks
    const int attn_blocks = BB * HH * (SS / 64);   // 1024 = 4/CU exactly

    const size_t need = (6 * per + 4 * wsz) * sizeof(short);
    if (ws_size >= need) {
        short* decb = ws + 4 * per;
        short* encb = ws + 5 * per;
        short* Wqb  = ws + 6 * per;
        short* Wkb  = Wqb + wsz;
        short* Wvb  = Wqb + 2 * wsz;
        short* Wpb  = Wqb + 3 * wsz;
        cvt6_kernel<<<dim3((BB * SS * DD / 8 + 255) / 256, 1, 6), 256, 0, stream>>>(
            dec, enc, Wq, Wk, Wv, Wp, decb, encb, Wqb, Wkb, Wvb, Wpb);
        qkv_gemm_kernel<1><<<qkv_grid, 256, 0, stream>>>(
            decb, encb, Wqb, Wkb, Wvb, bq, bk, bv, Qb, Kb, Vtb);
        attn_kernel<<<attn_blocks, 256, 0, stream>>>(Qb, Kb, Vtb, Yb);
        proj_gemm_kernel<1><<<proj_grid, 256, 0, stream>>>(Yb, Wpb, bp, (float*)d_out);
    } else {
        qkv_gemm_kernel<0><<<qkv_grid, 256, 0, stream>>>(
            dec, enc, Wq, Wk, Wv, bq, bk, bv, Qb, Kb, Vtb);
        attn_kernel<<<attn_blocks, 256, 0, stream>>>(Qb, Kb, Vtb, Yb);
        proj_gemm_kernel<0><<<proj_grid, 256, 0, stream>>>(Yb, Wp, bp, (float*)d_out);
    }
}

// Round 7
// 215.350 us; speedup vs baseline: 1.1176x; 1.1176x over previous
//
#include <hip/hip_runtime.h>
#include <hip/hip_bf16.h>
#include <cstdint>
#include <cstddef>

// Problem constants
#define BB 2
#define SS 2048
#define DD 1024
#define HH 16
#define HD 64

typedef __attribute__((ext_vector_type(8))) short bf16x8;
typedef __attribute__((ext_vector_type(4))) short bf16x4;
typedef __attribute__((ext_vector_type(4))) float f32x4;

// 16x16x16 bf16 MFMA (canonical _1k spelling; 4 bf16 per A/B operand)
#define MFMA16(va, vb, c) __builtin_amdgcn_mfma_f32_16x16x16bf16_1k(va, vb, c, 0, 0, 0)

// async global->LDS, 16B per lane, dest = wave-uniform base + lane*16
#define GLL(g, l) __builtin_amdgcn_global_load_lds( \
    (const __attribute__((address_space(1))) void*)(g), \
    (__attribute__((address_space(3))) void*)(l), 16, 0, 0)

// fast RTNE f32->bf16 (inputs guaranteed non-NaN in this problem)
__device__ __forceinline__ short f2bf_fast(float f) {
    uint32_t u = __float_as_uint(f);
    u += 0x7FFF + ((u >> 16) & 1);
    return (short)(u >> 16);
}
__device__ __forceinline__ uint32_t pack_bf2(float a, float b) {
    uint32_t ua = __float_as_uint(a), ub = __float_as_uint(b);
    ua += 0x7FFF + ((ua >> 16) & 1);
    ub += 0x7FFF + ((ub >> 16) & 1);
    return (ua >> 16) | (ub & 0xFFFF0000u);
}
// 8 fp32 -> 8 bf16 via two float4 loads, packed
__device__ __forceinline__ bf16x8 cvt8(const float* __restrict__ p) {
    float4 a = *(const float4*)p;
    float4 b = *(const float4*)(p + 4);
    union { uint32_t d[4]; bf16x8 v; } r;
    r.d[0] = pack_bf2(a.x, a.y);
    r.d[1] = pack_bf2(a.z, a.w);
    r.d[2] = pack_bf2(b.x, b.y);
    r.d[3] = pack_bf2(b.z, b.w);
    return r.v;
}

// ---------------- fp32 -> bf16 pre-convert (6 tensors, one dispatch) --------
__global__ __launch_bounds__(256) void cvt6_kernel(
    const float* __restrict__ s0, const float* __restrict__ s1,
    const float* __restrict__ s2, const float* __restrict__ s3,
    const float* __restrict__ s4, const float* __restrict__ s5,
    short* __restrict__ d0, short* __restrict__ d1, short* __restrict__ d2,
    short* __restrict__ d3, short* __restrict__ d4, short* __restrict__ d5)
{
    const int z = blockIdx.z;
    const float* s = (z == 0) ? s0 : (z == 1) ? s1 : (z == 2) ? s2
                   : (z == 3) ? s3 : (z == 4) ? s4 : s5;
    short* d = (z == 0) ? d0 : (z == 1) ? d1 : (z == 2) ? d2
             : (z == 3) ? d3 : (z == 4) ? d4 : d5;
    const int n8 = (z < 2) ? (BB * SS * DD / 8) : (DD * DD / 8);
    const int id = blockIdx.x * 256 + threadIdx.x;
    if (id >= n8) return;
    bf16x8 r = cvt8(s + (size_t)id * 8);
    *(uint4*)(d + (size_t)id * 8) = *(uint4*)&r;
}

// ---------------- fused QKV GEMM: 128x128 tile, z selects Q/K/V -------------
// z=0: Q -> [B,H,S,HD]; z=1: K -> [B,H,S,HD]; z=2: V -> [B,H,HD,S] (transposed)
template<int BF>
__global__ __launch_bounds__(256, 3) void qkv_gemm_kernel(
    const void* __restrict__ dec, const void* __restrict__ enc,
    const void* __restrict__ Wq, const void* __restrict__ Wk,
    const void* __restrict__ Wv,
    const float* __restrict__ bq, const float* __restrict__ bk,
    const float* __restrict__ bv,
    short* __restrict__ Qo, short* __restrict__ Ko, short* __restrict__ Vo)
{
    __shared__ short As[128 * 32];   // unpadded: required by global_load_lds
    __shared__ short Bs[128 * 32];

    const int z = blockIdx.z;
    const void* Xv = (z == 0) ? dec : enc;
    const void* Wp_ = (z == 0) ? Wq : (z == 1) ? Wk : Wv;
    const float* bias = (z == 0) ? bq : (z == 1) ? bk : bv;
    short* Yo = (z == 0) ? Qo : (z == 1) ? Ko : Vo;

    const int t = threadIdx.x;
    const int lane = t & 63, wv = t >> 6;
    const int lr = lane & 15, quad = lane >> 4;
    const int wm = wv >> 1, wn = wv & 1;
    const int m0 = blockIdx.y * 128;
    const int n0 = blockIdx.x * 128;
    const int K = DD;

    f32x4 acc[4][4];
    #pragma unroll
    for (int i = 0; i < 4; i++)
        #pragma unroll
        for (int j = 0; j < 4; j++) acc[i][j] = (f32x4){0.f, 0.f, 0.f, 0.f};

    for (int kb = 0; kb < K; kb += 32) {
        __syncthreads();
        if (BF) {
            const short* Xb = (const short*)Xv;
            const short* Wb = (const short*)Wp_;
            #pragma unroll
            for (int c = 0; c < 2; c++) {
                int r0 = wv * 32 + c * 16;              // 16 rows x 64B = 1KB/call
                int r = r0 + (lane >> 2), ch = (lane & 3) * 8;
                GLL(Xb + (size_t)(m0 + r) * K + kb + ch, &As[r0 * 32]);
                GLL(Wb + (size_t)(n0 + r) * K + kb + ch, &Bs[r0 * 32]);
            }
        } else {
            const float* Xf = (const float*)Xv;
            const float* Wf = (const float*)Wp_;
            #pragma unroll
            for (int c = 0; c < 2; c++) {
                int id = t + c * 256;
                int r = id >> 2, c8 = (id & 3) * 8;
                *(bf16x8*)&As[r * 32 + c8] = cvt8(Xf + (size_t)(m0 + r) * K + kb + c8);
                *(bf16x8*)&Bs[r * 32 + c8] = cvt8(Wf + (size_t)(n0 + r) * K + kb + c8);
            }
        }
        __syncthreads();

        bf16x8 af[4], bfr[4];
        #pragma unroll
        for (int mi = 0; mi < 4; mi++)
            af[mi] = *(const bf16x8*)&As[(wm * 64 + mi * 16 + lr) * 32 + quad * 8];
        #pragma unroll
        for (int ni = 0; ni < 4; ni++)
            bfr[ni] = *(const bf16x8*)&Bs[(wn * 64 + ni * 16 + lr) * 32 + quad * 8];
        #pragma unroll
        for (int mi = 0; mi < 4; mi++)
            #pragma unroll
            for (int ni = 0; ni < 4; ni++)
                acc[mi][ni] = __builtin_amdgcn_mfma_f32_16x16x32_bf16(
                    af[mi], bfr[ni], acc[mi][ni], 0, 0, 0);
    }

    if (z < 2) {
        #pragma unroll
        for (int ni = 0; ni < 4; ni++) {
            int col = n0 + wn * 64 + ni * 16 + lr;
            int h = col >> 6, hd = col & 63;
            float bvv = bias[col];
            #pragma unroll
            for (int mi = 0; mi < 4; mi++) {
                #pragma unroll
                for (int r2 = 0; r2 < 4; r2++) {
                    int row = m0 + wm * 64 + mi * 16 + quad * 4 + r2;
                    int b = row >> 11, s = row & 2047;
                    float v = acc[mi][ni][r2] + bvv;
                    size_t off = ((size_t)(b * HH + h) * SS + s) * HD + hd;
                    Yo[off] = f2bf_fast(v);
                }
            }
        }
    } else {
        // V: r2 indexes consecutive s -> pack 4 bf16 = 8B contiguous stores
        #pragma unroll
        for (int ni = 0; ni < 4; ni++) {
            int col = n0 + wn * 64 + ni * 16 + lr;
            int h = col >> 6, hd = col & 63;
            float bvv = bias[col];
            #pragma unroll
            for (int mi = 0; mi < 4; mi++) {
                int s0 = m0 + wm * 64 + mi * 16 + quad * 4;
                int b = s0 >> 11, s = s0 & 2047;
                union { uint32_t d[2]; } u;
                u.d[0] = pack_bf2(acc[mi][ni][0] + bvv, acc[mi][ni][1] + bvv);
                u.d[1] = pack_bf2(acc[mi][ni][2] + bvv, acc[mi][ni][3] + bvv);
                size_t off = ((size_t)(b * HH + h) * HD + hd) * SS + s;
                *(uint2*)(Yo + off) = *(uint2*)&u;
            }
        }
    }
}

// ---------------- output projection: 64x128 tile (512 blocks = 2/CU) -------
template<int WBF>
__global__ __launch_bounds__(256, 2) void proj_gemm_kernel(
    const short* __restrict__ X,
    const void* __restrict__ W, const float* __restrict__ bias,
    float* __restrict__ Y)
{
    __shared__ short As[64 * 32];
    __shared__ short Bs[128 * 32];

    const int t = threadIdx.x;
    const int lane = t & 63, wv = t >> 6;
    const int lr = lane & 15, quad = lane >> 4;
    const int wm = wv >> 1, wn = wv & 1;
    const int m0 = blockIdx.y * 64;
    const int n0 = blockIdx.x * 128;
    const int K = DD, N = DD;

    f32x4 acc[2][4];
    #pragma unroll
    for (int i = 0; i < 2; i++)
        #pragma unroll
        for (int j = 0; j < 4; j++) acc[i][j] = (f32x4){0.f, 0.f, 0.f, 0.f};

    for (int kb = 0; kb < K; kb += 32) {
        __syncthreads();
        {   // A: 4KB total, 1 call/wave (16 rows)
            int r0 = wv * 16;
            int r = r0 + (lane >> 2), ch = (lane & 3) * 8;
            GLL(X + (size_t)(m0 + r) * K + kb + ch, &As[r0 * 32]);
        }
        if (WBF) {
            const short* Wb = (const short*)W;
            #pragma unroll
            for (int c = 0; c < 2; c++) {
                int r0 = wv * 32 + c * 16;
                int r = r0 + (lane >> 2), ch = (lane & 3) * 8;
                GLL(Wb + (size_t)(n0 + r) * K + kb + ch, &Bs[r0 * 32]);
            }
        } else {
            const float* Wf = (const float*)W;
            #pragma unroll
            for (int c = 0; c < 2; c++) {
                int id = t + c * 256;
                int r = id >> 2, c8 = (id & 3) * 8;
                *(bf16x8*)&Bs[r * 32 + c8] = cvt8(Wf + (size_t)(n0 + r) * K + kb + c8);
            }
        }
        __syncthreads();

        bf16x8 af[2], bfr[4];
        #pragma unroll
        for (int mi = 0; mi < 2; mi++)
            af[mi] = *(const bf16x8*)&As[(wm * 32 + mi * 16 + lr) * 32 + quad * 8];
        #pragma unroll
        for (int ni = 0; ni < 4; ni++)
            bfr[ni] = *(const bf16x8*)&Bs[(wn * 64 + ni * 16 + lr) * 32 + quad * 8];
        #pragma unroll
        for (int mi = 0; mi < 2; mi++)
            #pragma unroll
            for (int ni = 0; ni < 4; ni++)
                acc[mi][ni] = __builtin_amdgcn_mfma_f32_16x16x32_bf16(
                    af[mi], bfr[ni], acc[mi][ni], 0, 0, 0);
    }

    #pragma unroll
    for (int ni = 0; ni < 4; ni++) {
        int col = n0 + wn * 64 + ni * 16 + lr;
        float bvv = bias[col];
        #pragma unroll
        for (int mi = 0; mi < 2; mi++) {
            #pragma unroll
            for (int r2 = 0; r2 < 4; r2++) {
                int row = m0 + wm * 32 + mi * 16 + quad * 4 + r2;
                Y[(size_t)row * N + col] = acc[mi][ni][r2] + bvv;
            }
        }
    }
}

// ---------------- flash attention, 32 queries/wave, register P --------------
// Q,K: [B*H, S, HD] bf16.  Vt_g: [B*H, HD, S] bf16.  Y: [B, S, D] bf16.
// S^T = K·Q^T: C-layout (q=lane&15, key=quad*4+reg) == B-operand layout of
// 16x16x16 MFMA. Each wave serves TWO 16-query groups so every K-frag/V-frag
// LDS read is amortized over 2 MFMAs (attn was LDS-throughput-bound).
__global__ __launch_bounds__(256, 2) void attn_kernel(
    const short* __restrict__ Q,
    const short* __restrict__ Kgl,
    const short* __restrict__ Vt_g,
    short* __restrict__ Y)
{
    __shared__ short Ks[128][72];     // [key][hd]
    __shared__ short Vt[64][136];     // [hd][key]

    const int t = threadIdx.x;
    const int lane = t & 63, w = t >> 6;
    const int lr = lane & 15, quad = lane >> 4;

    const int qt = blockIdx.x & 15;     // SS/128 = 16 query tiles of 128
    const int bh = blockIdx.x >> 4;
    const int b = bh >> 4, h = bh & 15;

    const float C = 0.125f * 1.44269504088896f;  // scale * log2(e)

    // two query groups per wave: qA = qt*128 + w*32 + lr, qB = qA + 16
    const short* QpA = Q + ((size_t)bh * SS + qt * 128 + w * 32 + lr) * HD;
    const short* QpB = QpA + 16 * HD;
    bf16x8 qfA0 = *(const bf16x8*)(QpA + quad * 8);
    bf16x8 qfA1 = *(const bf16x8*)(QpA + 32 + quad * 8);
    bf16x8 qfB0 = *(const bf16x8*)(QpB + quad * 8);
    bf16x8 qfB1 = *(const bf16x8*)(QpB + 32 + quad * 8);

    f32x4 oA[4], oB[4];   // O^T: d = dt*16 + quad*4 + reg, q = lr
    #pragma unroll
    for (int i = 0; i < 4; i++) {
        oA[i] = (f32x4){0.f, 0.f, 0.f, 0.f};
        oB[i] = (f32x4){0.f, 0.f, 0.f, 0.f};
    }
    float lsumA = 0.f, lsumB = 0.f;

    const uint4* Kg0 = (const uint4*)(Kgl + (size_t)bh * SS * HD);
    const short* Vg0 = Vt_g + (size_t)bh * HD * SS;

    for (int kt = 0; kt < SS / 128; kt++) {
        __syncthreads();   // prior iter's LDS reads done before overwrite
        const uint4* Kg = Kg0 + (size_t)kt * 128 * 8;
        #pragma unroll
        for (int c = 0; c < 4; c++) {           // K tile: 1024 16B chunks
            int id = t + c * 256;
            int row = id >> 3, h8 = id & 7;
            *(uint4*)&Ks[row][h8 * 8] = Kg[id];
        }
        #pragma unroll
        for (int c = 0; c < 4; c++) {           // V^T tile: 1024 16B chunks
            int id = t + c * 256;
            int hd = id >> 4, s16 = id & 15;
            *(uint4*)&Vt[hd][s16 * 8] =
                *(const uint4*)(Vg0 + (size_t)hd * SS + kt * 128 + s16 * 8);
        }
        __syncthreads();

        // S^T = K @ Q^T over 128 keys; each kf read feeds both query groups
        f32x4 scA[8], scB[8];
        #pragma unroll
        for (int nt = 0; nt < 8; nt++) {
            bf16x8 kf0 = *(const bf16x8*)&Ks[nt * 16 + lr][quad * 8];
            bf16x8 kf1 = *(const bf16x8*)&Ks[nt * 16 + lr][32 + quad * 8];
            scA[nt] = __builtin_amdgcn_mfma_f32_16x16x32_bf16(
                kf0, qfA0, (f32x4){0.f, 0.f, 0.f, 0.f}, 0, 0, 0);
            scA[nt] = __builtin_amdgcn_mfma_f32_16x16x32_bf16(kf1, qfA1, scA[nt], 0, 0, 0);
            scB[nt] = __builtin_amdgcn_mfma_f32_16x16x32_bf16(
                kf0, qfB0, (f32x4){0.f, 0.f, 0.f, 0.f}, 0, 0, 0);
            scB[nt] = __builtin_amdgcn_mfma_f32_16x16x32_bf16(kf1, qfB1, scB[nt], 0, 0, 0);
        }

        // P^T = exp2(S^T * C) in registers -> 16x16x16 B-frags
        bf16x4 pbA[8], pbB[8];
        #pragma unroll
        for (int nt = 0; nt < 8; nt++) {
            float a0 = __builtin_amdgcn_exp2f(scA[nt][0] * C);
            float a1 = __builtin_amdgcn_exp2f(scA[nt][1] * C);
            float a2 = __builtin_amdgcn_exp2f(scA[nt][2] * C);
            float a3 = __builtin_amdgcn_exp2f(scA[nt][3] * C);
            lsumA += (a0 + a1) + (a2 + a3);
            union { uint32_t d[2]; bf16x4 v; } ua;
            ua.d[0] = pack_bf2(a0, a1);
            ua.d[1] = pack_bf2(a2, a3);
            pbA[nt] = ua.v;
            float b0 = __builtin_amdgcn_exp2f(scB[nt][0] * C);
            float b1 = __builtin_amdgcn_exp2f(scB[nt][1] * C);
            float b2 = __builtin_amdgcn_exp2f(scB[nt][2] * C);
            float b3 = __builtin_amdgcn_exp2f(scB[nt][3] * C);
            lsumB += (b0 + b1) + (b2 + b3);
            union { uint32_t d[2]; bf16x4 v; } ub;
            ub.d[0] = pack_bf2(b0, b1);
            ub.d[1] = pack_bf2(b2, b3);
            pbB[nt] = ub.v;
        }

        // O^T += V^T @ P^T ; each va read feeds both groups
        #pragma unroll
        for (int dt = 0; dt < 4; dt++) {
            #pragma unroll
            for (int nt = 0; nt < 8; nt++) {
                bf16x4 va = *(const bf16x4*)&Vt[dt * 16 + lr][nt * 16 + quad * 4];
                oA[dt] = MFMA16(va, pbA[nt], oA[dt]);
                oB[dt] = MFMA16(va, pbB[nt], oB[dt]);
            }
        }
    }

    // full row-sums: combine the 4 quads holding q=lr
    lsumA += __shfl_xor(lsumA, 16, 64);
    lsumA += __shfl_xor(lsumA, 32, 64);
    lsumB += __shfl_xor(lsumB, 16, 64);
    lsumB += __shfl_xor(lsumB, 32, 64);
    float invA = 1.0f / lsumA, invB = 1.0f / lsumB;

    // O^T -> Y[b][s=q][h*64+d]; 4 consecutive d per lane -> 8B stores
    const int srowA = qt * 128 + w * 32 + lr;
    short* YpA = Y + ((size_t)b * SS + srowA) * DD + h * 64 + quad * 4;
    short* YpB = YpA + 16 * DD;
    #pragma unroll
    for (int dt = 0; dt < 4; dt++) {
        union { uint32_t d[2]; } ua;
        ua.d[0] = pack_bf2(oA[dt][0] * invA, oA[dt][1] * invA);
        ua.d[1] = pack_bf2(oA[dt][2] * invA, oA[dt][3] * invA);
        *(uint2*)(YpA + dt * 16) = *(uint2*)&ua;
        union { uint32_t d[2]; } ub;
        ub.d[0] = pack_bf2(oB[dt][0] * invB, oB[dt][1] * invB);
        ub.d[1] = pack_bf2(oB[dt][2] * invB, oB[dt][3] * invB);
        *(uint2*)(YpB + dt * 16) = *(uint2*)&ub;
    }
}

extern "C" void kernel_launch(void* const* d_in, const int* in_sizes, int n_in,
                              void* d_out, int out_size, void* d_ws, size_t ws_size,
                              hipStream_t stream) {
    const float* dec = (const float*)d_in[0];
    const float* enc = (const float*)d_in[1];
    const float* Wq  = (const float*)d_in[2];
    const float* bq  = (const float*)d_in[3];
    const float* Wk  = (const float*)d_in[4];
    const float* bk  = (const float*)d_in[5];
    const float* Wv  = (const float*)d_in[6];
    const float* bv  = (const float*)d_in[7];
    const float* Wp  = (const float*)d_in[8];
    const float* bp  = (const float*)d_in[9];

    const size_t per = (size_t)BB * HH * SS * HD;  // 4,194,304
    const size_t wsz = (size_t)DD * DD;            // 1,048,576
    short* ws = (short*)d_ws;
    short* Qb  = ws;
    short* Kb  = ws + per;
    short* Vtb = ws + 2 * per;
    short* Yb  = ws + 3 * per;

    dim3 qkv_grid(DD / 128, (BB * SS) / 128, 3);   // 768 blocks = 3/CU
    dim3 proj_grid(DD / 128, (BB * SS) / 64);      // 512 blocks = 2/CU
    const int attn_blocks = BB * HH * (SS / 128);  // 512 = 2/CU

    const size_t need = (6 * per + 4 * wsz) * sizeof(short);
    if (ws_size >= need) {
        short* decb = ws + 4 * per;
        short* encb = ws + 5 * per;
        short* Wqb  = ws + 6 * per;
        short* Wkb  = Wqb + wsz;
        short* Wvb  = Wqb + 2 * wsz;
        short* Wpb  = Wqb + 3 * wsz;
        cvt6_kernel<<<dim3((BB * SS * DD / 8 + 255) / 256, 1, 6), 256, 0, stream>>>(
            dec, enc, Wq, Wk, Wv, Wp, decb, encb, Wqb, Wkb, Wvb, Wpb);
        qkv_gemm_kernel<1><<<qkv_grid, 256, 0, stream>>>(
            decb, encb, Wqb, Wkb, Wvb, bq, bk, bv, Qb, Kb, Vtb);
        attn_kernel<<<attn_blocks, 256, 0, stream>>>(Qb, Kb, Vtb, Yb);
        proj_gemm_kernel<1><<<proj_grid, 256, 0, stream>>>(Yb, Wpb, bp, (float*)d_out);
    } else {
        qkv_gemm_kernel<0><<<qkv_grid, 256, 0, stream>>>(
            dec, enc, Wq, Wk, Wv, bq, bk, bv, Qb, Kb, Vtb);
        attn_kernel<<<attn_blocks, 256, 0, stream>>>(Qb, Kb, Vtb, Yb);
        proj_gemm_kernel<0><<<proj_grid, 256, 0, stream>>>(Yb, Wp, bp, (float*)d_out);
    }
}